// Round 1
// baseline (349.467 us; speedup 1.0000x reference)
//
#include <hip/hip_runtime.h>
#include <hip/hip_bf16.h>
#include <math.h>

typedef __attribute__((ext_vector_type(8))) __bf16 bf16x8;
typedef __attribute__((ext_vector_type(4))) float f32x4;

#define NTOK 8192
#define DIN 1024
#define DOUT 1024
#define KAUG 4096
#define SEH 32

static __device__ __forceinline__ unsigned short f2bf(float f) {
  union { float f; unsigned u; } v; v.f = f;
  unsigned r = (v.u + 0x7FFFu + ((v.u >> 16) & 1u)) >> 16;
  return (unsigned short)r;
}

// A_aug[n][i*4 + {0..3}] = { x, b0/s, b1/s, b2/s }  (bf16)
__global__ __launch_bounds__(256) void build_aaug(const float* __restrict__ x,
                                                  ushort* __restrict__ Aaug) {
  const int id = blockIdx.x * 256 + threadIdx.x;  // over NTOK*DIN
  const float v = x[id];
  const float d0 = fabsf(v + 1.f), d1 = fabsf(v), d2 = fabsf(v - 1.f);
  float b0 = (d0 < 1.f) ? (1.f - d0) * (1.f - d0) : 0.f;
  float b1 = (d1 < 1.f) ? (1.f - d1) * (1.f - d1) : 0.f;
  float b2 = (d2 < 1.f) ? (1.f - d2) * (1.f - d2) : 0.f;
  const float inv = 1.f / (b0 + b1 + b2 + 1e-6f);
  ushort4 o;
  o.x = f2bf(v);
  o.y = f2bf(b0 * inv);
  o.z = f2bf(b1 * inv);
  o.w = f2bf(b2 * inv);
  ((ushort4*)Aaug)[id] = o;  // elements id*4 .. id*4+3 == n*4096 + i*4
}

// W_aug[o][i*4 + {0..3}] = { base_w[o,i], spline_w[o,i,0..2] }  (bf16)
__global__ __launch_bounds__(256) void pack_w(const float* __restrict__ bw,
                                              const float* __restrict__ sw,
                                              ushort* __restrict__ Waug) {
  const int id = blockIdx.x * 256 + threadIdx.x;  // over DOUT*DIN
  const float b = bw[id];
  const float s0 = sw[id * 3 + 0];
  const float s1 = sw[id * 3 + 1];
  const float s2 = sw[id * 3 + 2];
  ushort4 o;
  o.x = f2bf(b);
  o.y = f2bf(s0);
  o.z = f2bf(s1);
  o.w = f2bf(s2);
  ((ushort4*)Waug)[id] = o;
}

// C[8192][1024] = A[8192][4096] * B[1024][4096]^T   (bf16 in, f32 out)
// 128x128 tile, BK=64, 4 waves (2x2), 4x4 16x16x32 fragments per wave.
__global__ __launch_bounds__(256) void gemm_bt(const ushort* __restrict__ A,
                                               const ushort* __restrict__ B,
                                               float* __restrict__ C) {
  __shared__ ushort As[128 * 64];
  __shared__ ushort Bs[128 * 64];
  const int bm = blockIdx.x >> 3;  // 64 row-blocks
  const int bn = blockIdx.x & 7;   // 8 col-blocks
  const int tid = threadIdx.x;
  const int wid = tid >> 6;
  const int lane = tid & 63;
  const int l16 = lane & 15;
  const int lk = lane >> 4;
  const int wr = wid >> 1;
  const int wc = wid & 1;

  f32x4 acc[4][4] = {};

  const ushort* Ab = A + (size_t)(bm * 128) * KAUG;
  const ushort* Bb = B + (size_t)(bn * 128) * KAUG;

  for (int k0 = 0; k0 < KAUG; k0 += 64) {
    // stage A tile: 128 rows x 64 k (16 KB) = 1024 chunks of 16B, 4 rounds
#pragma unroll
    for (int r = 0; r < 4; ++r) {
      const int c = r * 256 + wid * 64 + lane;
      const int row = c >> 3, kc = c & 7;
      __builtin_amdgcn_global_load_lds(
          (__attribute__((address_space(1))) const void*)(Ab + (size_t)row * KAUG + k0 + kc * 8),
          (__attribute__((address_space(3))) void*)(As + (r * 256 + wid * 64) * 8),
          16, 0, 0);
    }
#pragma unroll
    for (int r = 0; r < 4; ++r) {
      const int c = r * 256 + wid * 64 + lane;
      const int row = c >> 3, kc = c & 7;
      __builtin_amdgcn_global_load_lds(
          (__attribute__((address_space(1))) const void*)(Bb + (size_t)row * KAUG + k0 + kc * 8),
          (__attribute__((address_space(3))) void*)(Bs + (r * 256 + wid * 64) * 8),
          16, 0, 0);
    }
    __syncthreads();

#pragma unroll
    for (int kk = 0; kk < 64; kk += 32) {
      bf16x8 af[4], bfr[4];
#pragma unroll
      for (int m = 0; m < 4; ++m)
        af[m] = *(const bf16x8*)(As + (wr * 64 + m * 16 + l16) * 64 + kk + lk * 8);
#pragma unroll
      for (int n = 0; n < 4; ++n)
        bfr[n] = *(const bf16x8*)(Bs + (wc * 64 + n * 16 + l16) * 64 + kk + lk * 8);
#pragma unroll
      for (int m = 0; m < 4; ++m)
#pragma unroll
        for (int n = 0; n < 4; ++n)
          acc[m][n] = __builtin_amdgcn_mfma_f32_16x16x32_bf16(af[m], bfr[n], acc[m][n], 0, 0, 0);
    }
    __syncthreads();
  }

  // C/D layout: col = lane&15, row = (lane>>4)*4 + reg
  float* Cb = C + (size_t)(bm * 128 + wr * 64) * DOUT + bn * 128 + wc * 64;
#pragma unroll
  for (int m = 0; m < 4; ++m)
#pragma unroll
    for (int n = 0; n < 4; ++n)
#pragma unroll
      for (int j = 0; j < 4; ++j)
        Cb[(size_t)(m * 16 + lk * 4 + j) * DOUT + n * 16 + l16] = acc[m][n][j];
}

// per-token LayerNorm + SE gate, in-place on out. 1 block (256 thr) per token.
__global__ __launch_bounds__(256) void ln_se(float* __restrict__ out,
                                             const float* __restrict__ ln_w,
                                             const float* __restrict__ ln_b,
                                             const float* __restrict__ se_w1,
                                             const float* __restrict__ se_b1,
                                             const float* __restrict__ se_w2,
                                             const float* __restrict__ se_b2) {
  __shared__ float y[DOUT];
  __shared__ float red[8];
  __shared__ float h[SEH];
  const int t = threadIdx.x;
  float* row = out + (size_t)blockIdx.x * DOUT;
  const float4 v = ((const float4*)row)[t];
  float s = v.x + v.y + v.z + v.w;
  float ss = v.x * v.x + v.y * v.y + v.z * v.z + v.w * v.w;
#pragma unroll
  for (int off = 32; off > 0; off >>= 1) {
    s += __shfl_down(s, off);
    ss += __shfl_down(ss, off);
  }
  if ((t & 63) == 0) {
    red[t >> 6] = s;
    red[4 + (t >> 6)] = ss;
  }
  __syncthreads();
  s = red[0] + red[1] + red[2] + red[3];
  ss = red[4] + red[5] + red[6] + red[7];
  const float mu = s * (1.f / (float)DOUT);
  const float var = ss * (1.f / (float)DOUT) - mu * mu;
  const float inv = rsqrtf(var + 1e-5f);
  const float4 lw = ((const float4*)ln_w)[t];
  const float4 lb = ((const float4*)ln_b)[t];
  float4 yv;
  yv.x = (v.x - mu) * inv * lw.x + lb.x;
  yv.y = (v.y - mu) * inv * lw.y + lb.y;
  yv.z = (v.z - mu) * inv * lw.z + lb.z;
  yv.w = (v.w - mu) * inv * lw.w + lb.w;
  ((float4*)y)[t] = yv;
  __syncthreads();

  // SE1: h[j] = relu(sum_c y[c]*w1[j,c] + b1[j]); 8 threads per j
  const int j = t >> 3, part = t & 7;
  const float4* w1 = (const float4*)(se_w1 + (j << 10) + (part << 7));
  const float4* yp = (const float4*)(y + (part << 7));
  float hs = 0.f;
#pragma unroll
  for (int c2 = 0; c2 < 32; ++c2) {
    const float4 a = yp[c2], b = w1[c2];
    hs += a.x * b.x + a.y * b.y + a.z * b.z + a.w * b.w;
  }
  hs += __shfl_xor(hs, 1);
  hs += __shfl_xor(hs, 2);
  hs += __shfl_xor(hs, 4);
  if (part == 0) h[j] = fmaxf(hs + se_b1[j], 0.f);
  __syncthreads();

  // SE2: se[c] = sigmoid(sum_j h[j]*w2[c,j] + b2[c]); out = y * se
  float o4[4];
#pragma unroll
  for (int cc = 0; cc < 4; ++cc) {
    const int c = (t << 2) + cc;
    float s2 = se_b2[c];
    const float4* w2 = (const float4*)(se_w2 + (c << 5));
#pragma unroll
    for (int jj = 0; jj < 8; ++jj) {
      const float4 b = w2[jj];
      s2 += h[jj * 4 + 0] * b.x + h[jj * 4 + 1] * b.y + h[jj * 4 + 2] * b.z +
            h[jj * 4 + 3] * b.w;
    }
    o4[cc] = 1.f / (1.f + __expf(-s2));
  }
  float4 res;
  res.x = yv.x * o4[0];
  res.y = yv.y * o4[1];
  res.z = yv.z * o4[2];
  res.w = yv.w * o4[3];
  ((float4*)row)[t] = res;
}

extern "C" void kernel_launch(void* const* d_in, const int* in_sizes, int n_in,
                              void* d_out, int out_size, void* d_ws, size_t ws_size,
                              hipStream_t stream) {
  const float* x = (const float*)d_in[0];
  const float* bw = (const float*)d_in[1];
  const float* sw = (const float*)d_in[2];
  const float* ln_w = (const float*)d_in[3];
  const float* ln_b = (const float*)d_in[4];
  const float* se_w1 = (const float*)d_in[5];
  const float* se_b1 = (const float*)d_in[6];
  const float* se_w2 = (const float*)d_in[7];
  const float* se_b2 = (const float*)d_in[8];
  float* out = (float*)d_out;

  ushort* Aaug = (ushort*)d_ws;                       // 8192*4096 bf16 = 64 MB
  ushort* Waug = Aaug + (size_t)NTOK * KAUG;          // 1024*4096 bf16 = 8 MB

  build_aaug<<<NTOK * DIN / 256, 256, 0, stream>>>(x, Aaug);
  pack_w<<<DOUT * DIN / 256, 256, 0, stream>>>(bw, sw, Waug);
  gemm_bt<<<(NTOK / 128) * (DOUT / 128), 256, 0, stream>>>(Aaug, Waug, out);
  ln_se<<<NTOK, 256, 0, stream>>>(out, ln_w, ln_b, se_w1, se_b1, se_w2, se_b2);
}

// Round 2
// 203.438 us; speedup vs baseline: 1.7178x; 1.7178x over previous
//
#include <hip/hip_runtime.h>
#include <hip/hip_bf16.h>
#include <math.h>

typedef __attribute__((ext_vector_type(8))) __bf16 bf16x8;
typedef __attribute__((ext_vector_type(4))) float f32x4;

#define NTOK 8192
#define DIN 1024
#define DOUT 1024
#define KAUG 4096
#define SEH 32

static __device__ __forceinline__ unsigned short f2bf(float f) {
  union { float f; unsigned u; } v; v.f = f;
  unsigned r = (v.u + 0x7FFFu + ((v.u >> 16) & 1u)) >> 16;
  return (unsigned short)r;
}
static __device__ __forceinline__ float bflo(unsigned u) {
  union { unsigned u; float f; } v; v.u = u << 16; return v.f;
}
static __device__ __forceinline__ float bfhi(unsigned u) {
  union { unsigned u; float f; } v; v.u = u & 0xFFFF0000u; return v.f;
}

// A_aug[n][i*4 + {0..3}] = { x, b0/s, b1/s, b2/s }  (bf16)
__global__ __launch_bounds__(256) void build_aaug(const float* __restrict__ x,
                                                  ushort* __restrict__ Aaug) {
  const int id = blockIdx.x * 256 + threadIdx.x;  // over NTOK*DIN
  const float v = x[id];
  const float d0 = fabsf(v + 1.f), d1 = fabsf(v), d2 = fabsf(v - 1.f);
  float b0 = (d0 < 1.f) ? (1.f - d0) * (1.f - d0) : 0.f;
  float b1 = (d1 < 1.f) ? (1.f - d1) * (1.f - d1) : 0.f;
  float b2 = (d2 < 1.f) ? (1.f - d2) * (1.f - d2) : 0.f;
  const float inv = 1.f / (b0 + b1 + b2 + 1e-6f);
  ushort4 o;
  o.x = f2bf(v);
  o.y = f2bf(b0 * inv);
  o.z = f2bf(b1 * inv);
  o.w = f2bf(b2 * inv);
  ((ushort4*)Aaug)[id] = o;
}

// W_aug[o][i*4 + {0..3}] = { base_w[o,i], spline_w[o,i,0..2] }  (bf16)
__global__ __launch_bounds__(256) void pack_w(const float* __restrict__ bw,
                                              const float* __restrict__ sw,
                                              ushort* __restrict__ Waug) {
  const int id = blockIdx.x * 256 + threadIdx.x;  // over DOUT*DIN
  ushort4 o;
  o.x = f2bf(bw[id]);
  o.y = f2bf(sw[id * 3 + 0]);
  o.z = f2bf(sw[id * 3 + 1]);
  o.w = f2bf(sw[id * 3 + 2]);
  ((ushort4*)Waug)[id] = o;
}

// pack SE weights to bf16: w1 [32][1024], w2 [1024][32]
__global__ __launch_bounds__(256) void pack_se(const float* __restrict__ w1,
                                               const float* __restrict__ w2,
                                               ushort* __restrict__ w1b,
                                               ushort* __restrict__ w2b) {
  const int id = blockIdx.x * 256 + threadIdx.x;  // 0..65535
  if (id < SEH * DOUT) w1b[id] = f2bf(w1[id]);
  else w2b[id - SEH * DOUT] = f2bf(w2[id - SEH * DOUT]);
}

// C[8192][1024] = A[8192][4096] * B[1024][4096]^T   (bf16 in, f32 out)
__global__ __launch_bounds__(256) void gemm_bt(const ushort* __restrict__ A,
                                               const ushort* __restrict__ B,
                                               float* __restrict__ C) {
  __shared__ ushort As[128 * 64];
  __shared__ ushort Bs[128 * 64];
  const int bm = blockIdx.x >> 3;
  const int bn = blockIdx.x & 7;
  const int tid = threadIdx.x;
  const int wid = tid >> 6;
  const int lane = tid & 63;
  const int l16 = lane & 15;
  const int lk = lane >> 4;
  const int wr = wid >> 1;
  const int wc = wid & 1;

  f32x4 acc[4][4] = {};

  const ushort* Ab = A + (size_t)(bm * 128) * KAUG;
  const ushort* Bb = B + (size_t)(bn * 128) * KAUG;

  for (int k0 = 0; k0 < KAUG; k0 += 64) {
#pragma unroll
    for (int r = 0; r < 4; ++r) {
      const int c = r * 256 + wid * 64 + lane;
      const int row = c >> 3, kc = c & 7;
      __builtin_amdgcn_global_load_lds(
          (__attribute__((address_space(1))) const void*)(Ab + (size_t)row * KAUG + k0 + kc * 8),
          (__attribute__((address_space(3))) void*)(As + (r * 256 + wid * 64) * 8),
          16, 0, 0);
    }
#pragma unroll
    for (int r = 0; r < 4; ++r) {
      const int c = r * 256 + wid * 64 + lane;
      const int row = c >> 3, kc = c & 7;
      __builtin_amdgcn_global_load_lds(
          (__attribute__((address_space(1))) const void*)(Bb + (size_t)row * KAUG + k0 + kc * 8),
          (__attribute__((address_space(3))) void*)(Bs + (r * 256 + wid * 64) * 8),
          16, 0, 0);
    }
    __syncthreads();

#pragma unroll
    for (int kk = 0; kk < 64; kk += 32) {
      bf16x8 af[4], bfr[4];
#pragma unroll
      for (int m = 0; m < 4; ++m)
        af[m] = *(const bf16x8*)(As + (wr * 64 + m * 16 + l16) * 64 + kk + lk * 8);
#pragma unroll
      for (int n = 0; n < 4; ++n)
        bfr[n] = *(const bf16x8*)(Bs + (wc * 64 + n * 16 + l16) * 64 + kk + lk * 8);
#pragma unroll
      for (int m = 0; m < 4; ++m)
#pragma unroll
        for (int n = 0; n < 4; ++n)
          acc[m][n] = __builtin_amdgcn_mfma_f32_16x16x32_bf16(af[m], bfr[n], acc[m][n], 0, 0, 0);
    }
    __syncthreads();
  }

  float* Cb = C + (size_t)(bm * 128 + wr * 64) * DOUT + bn * 128 + wc * 64;
#pragma unroll
  for (int m = 0; m < 4; ++m)
#pragma unroll
    for (int n = 0; n < 4; ++n)
#pragma unroll
      for (int j = 0; j < 4; ++j)
        Cb[(size_t)(m * 16 + lk * 4 + j) * DOUT + n * 16 + l16] = acc[m][n][j];
}

// Fused LayerNorm + SE gate, one WAVE per token, all-register, no LDS/barriers.
// Lane owns columns c = (lane + 64*h)*8 + e, h in {0,1}, e in {0..7}.
__global__ __launch_bounds__(256) void ln_se_fused(
    float* __restrict__ out,
    const float* __restrict__ ln_w, const float* __restrict__ ln_b,
    const ushort* __restrict__ w1b, const float* __restrict__ se_b1,
    const ushort* __restrict__ w2b, const float* __restrict__ se_b2) {
  const int lane = threadIdx.x & 63;
  const int t = blockIdx.x * 4 + (threadIdx.x >> 6);
  float* row = out + (size_t)t * DOUT;

  float y[16];
#pragma unroll
  for (int h = 0; h < 2; ++h) {
    const float4 a = ((const float4*)row)[(lane + 64 * h) * 2];
    const float4 b = ((const float4*)row)[(lane + 64 * h) * 2 + 1];
    y[h * 8 + 0] = a.x; y[h * 8 + 1] = a.y; y[h * 8 + 2] = a.z; y[h * 8 + 3] = a.w;
    y[h * 8 + 4] = b.x; y[h * 8 + 5] = b.y; y[h * 8 + 6] = b.z; y[h * 8 + 7] = b.w;
  }
  float s = 0.f, ss = 0.f;
#pragma unroll
  for (int e = 0; e < 16; ++e) { s += y[e]; ss += y[e] * y[e]; }
#pragma unroll
  for (int m = 32; m; m >>= 1) { s += __shfl_xor(s, m); ss += __shfl_xor(ss, m); }
  const float mu = s * (1.f / (float)DOUT);
  const float inv = rsqrtf(ss * (1.f / (float)DOUT) - mu * mu + 1e-5f);

#pragma unroll
  for (int h = 0; h < 2; ++h) {
    const float4 lw0 = ((const float4*)ln_w)[(lane + 64 * h) * 2];
    const float4 lw1 = ((const float4*)ln_w)[(lane + 64 * h) * 2 + 1];
    const float4 lb0 = ((const float4*)ln_b)[(lane + 64 * h) * 2];
    const float4 lb1 = ((const float4*)ln_b)[(lane + 64 * h) * 2 + 1];
    y[h * 8 + 0] = (y[h * 8 + 0] - mu) * inv * lw0.x + lb0.x;
    y[h * 8 + 1] = (y[h * 8 + 1] - mu) * inv * lw0.y + lb0.y;
    y[h * 8 + 2] = (y[h * 8 + 2] - mu) * inv * lw0.z + lb0.z;
    y[h * 8 + 3] = (y[h * 8 + 3] - mu) * inv * lw0.w + lb0.w;
    y[h * 8 + 4] = (y[h * 8 + 4] - mu) * inv * lw1.x + lb1.x;
    y[h * 8 + 5] = (y[h * 8 + 5] - mu) * inv * lw1.y + lb1.y;
    y[h * 8 + 6] = (y[h * 8 + 6] - mu) * inv * lw1.z + lb1.z;
    y[h * 8 + 7] = (y[h * 8 + 7] - mu) * inv * lw1.w + lb1.w;
  }

  // SE1: h[j] = relu(dot1024(y_row, w1[j]) + b1[j]) — partial per lane, butterfly.
  float hj[32];
#pragma unroll
  for (int j = 0; j < 32; ++j) {
    float p = 0.f;
#pragma unroll
    for (int h = 0; h < 2; ++h) {
      const uint4 w = *(const uint4*)(w1b + j * DOUT + (lane + 64 * h) * 8);
      p += y[h * 8 + 0] * bflo(w.x) + y[h * 8 + 1] * bfhi(w.x)
         + y[h * 8 + 2] * bflo(w.y) + y[h * 8 + 3] * bfhi(w.y)
         + y[h * 8 + 4] * bflo(w.z) + y[h * 8 + 5] * bfhi(w.z)
         + y[h * 8 + 6] * bflo(w.w) + y[h * 8 + 7] * bfhi(w.w);
    }
    hj[j] = p;
  }
#pragma unroll
  for (int m = 32; m; m >>= 1)
#pragma unroll
    for (int j = 0; j < 32; ++j) hj[j] += __shfl_xor(hj[j], m);
#pragma unroll
  for (int j = 0; j < 32; ++j) hj[j] = fmaxf(hj[j] + se_b1[j], 0.f);

  // SE2: out[c] = y[c] * sigmoid(dot32(h, w2[c]) + b2[c])
#pragma unroll
  for (int h = 0; h < 2; ++h) {
    float o[8];
#pragma unroll
    for (int e = 0; e < 8; ++e) {
      const int c = (lane + 64 * h) * 8 + e;
      const uint4* wp = (const uint4*)(w2b + (size_t)c * SEH);
      const uint4 wa = wp[0], wb = wp[1], wc2 = wp[2], wd = wp[3];
      float g = se_b2[c];
      g += hj[0] * bflo(wa.x) + hj[1] * bfhi(wa.x) + hj[2] * bflo(wa.y) + hj[3] * bfhi(wa.y)
         + hj[4] * bflo(wa.z) + hj[5] * bfhi(wa.z) + hj[6] * bflo(wa.w) + hj[7] * bfhi(wa.w);
      g += hj[8] * bflo(wb.x) + hj[9] * bfhi(wb.x) + hj[10] * bflo(wb.y) + hj[11] * bfhi(wb.y)
         + hj[12] * bflo(wb.z) + hj[13] * bfhi(wb.z) + hj[14] * bflo(wb.w) + hj[15] * bfhi(wb.w);
      g += hj[16] * bflo(wc2.x) + hj[17] * bfhi(wc2.x) + hj[18] * bflo(wc2.y) + hj[19] * bfhi(wc2.y)
         + hj[20] * bflo(wc2.z) + hj[21] * bfhi(wc2.z) + hj[22] * bflo(wc2.w) + hj[23] * bfhi(wc2.w);
      g += hj[24] * bflo(wd.x) + hj[25] * bfhi(wd.x) + hj[26] * bflo(wd.y) + hj[27] * bfhi(wd.y)
         + hj[28] * bflo(wd.z) + hj[29] * bfhi(wd.z) + hj[30] * bflo(wd.w) + hj[31] * bfhi(wd.w);
      o[e] = y[h * 8 + e] / (1.f + __expf(-g));
    }
    float4 s0, s1;
    s0.x = o[0]; s0.y = o[1]; s0.z = o[2]; s0.w = o[3];
    s1.x = o[4]; s1.y = o[5]; s1.z = o[6]; s1.w = o[7];
    ((float4*)row)[(lane + 64 * h) * 2] = s0;
    ((float4*)row)[(lane + 64 * h) * 2 + 1] = s1;
  }
}

extern "C" void kernel_launch(void* const* d_in, const int* in_sizes, int n_in,
                              void* d_out, int out_size, void* d_ws, size_t ws_size,
                              hipStream_t stream) {
  const float* x = (const float*)d_in[0];
  const float* bw = (const float*)d_in[1];
  const float* sw = (const float*)d_in[2];
  const float* ln_w = (const float*)d_in[3];
  const float* ln_b = (const float*)d_in[4];
  const float* se_w1 = (const float*)d_in[5];
  const float* se_b1 = (const float*)d_in[6];
  const float* se_w2 = (const float*)d_in[7];
  const float* se_b2 = (const float*)d_in[8];
  float* out = (float*)d_out;

  ushort* Aaug = (ushort*)d_ws;                        // 64 MB
  ushort* Waug = Aaug + (size_t)NTOK * KAUG;           // 8 MB
  ushort* w1b = Waug + (size_t)DOUT * KAUG;            // 64 KB
  ushort* w2b = w1b + SEH * DOUT;                      // 64 KB

  build_aaug<<<NTOK * DIN / 256, 256, 0, stream>>>(x, Aaug);
  pack_w<<<DOUT * DIN / 256, 256, 0, stream>>>(bw, sw, Waug);
  pack_se<<<2 * SEH * DOUT / 256, 256, 0, stream>>>(se_w1, se_w2, w1b, w2b);
  gemm_bt<<<(NTOK / 128) * (DOUT / 128), 256, 0, stream>>>(Aaug, Waug, out);
  ln_se_fused<<<NTOK / 4, 256, 0, stream>>>(out, ln_w, ln_b, w1b, se_b1, w2b, se_b2);
}